// Round 3
// baseline (313.142 us; speedup 1.0000x reference)
//
#include <hip/hip_runtime.h>

#define E_EDGES 327680
#define D 128
#define BM 128      // edges per block
#define NW 4        // waves per block (each wave owns 32 edges)

typedef __bf16 bf16x8 __attribute__((ext_vector_type(8)));
typedef float  f32x4  __attribute__((ext_vector_type(4)));

// d_ws layout (bf16 weight fragments, B-operand order for mfma_f32_16x16x32_bf16):
//   per (kblock, ntile): 64 lanes x 16B, lane l holds W[k0+(l>>4)*8+j][ntile*16+(l&15)]
//   L1: kblocks 0..11 used (12..15 slot reused for b1p); L2/3/4: 4 kblocks each.
#define L1_OFF 0
#define L2_OFF 131072
#define L3_OFF 163840
#define L4_OFF 196608
#define B1P_US 49152   // u16 offset of f32 b1p[128] (= byte 98304, old L1 kblock-12 slot)

__device__ __forceinline__ unsigned short f2bf(float f) {
  unsigned int u = __builtin_bit_cast(unsigned int, f);
  u += 0x7fffu + ((u >> 16) & 1u);   // round-to-nearest-even
  return (unsigned short)(u >> 16);
}

__device__ __forceinline__ unsigned int cvtpk(float lo, float hi) {
  unsigned int r;
  asm("v_cvt_pk_bf16_f32 %0, %1, %2" : "=v"(r) : "v"(lo), "v"(hi));
  return r;
}

__device__ __forceinline__ bf16x8 cvt8(float4 a, float4 b) {
  union { unsigned int u[4]; bf16x8 v; } r;
  r.u[0] = cvtpk(a.x, a.y);
  r.u[1] = cvtpk(a.z, a.w);
  r.u[2] = cvtpk(b.x, b.y);
  r.u[3] = cvtpk(b.z, b.w);
  return r.v;
}

__global__ __launch_bounds__(256) void prep_weights(
    const float* __restrict__ W1, const float* __restrict__ W2,
    const float* __restrict__ W3, const float* __restrict__ W4,
    const float* __restrict__ b1, const float* __restrict__ glob,
    unsigned short* __restrict__ ws)
{
  if (blockIdx.x == 56) {
    // b1p[n] = b1[n] + sum_j g[j] * W1[384+j][n]
    int n = threadIdx.x;
    if (n < D) {
      float s = b1[n];
      for (int j = 0; j < D; ++j) s += glob[j] * W1[(size_t)(384 + j) * D + n];
      ((float*)(ws + B1P_US))[n] = s;
    }
    return;
  }
  int tid = blockIdx.x * 256 + threadIdx.x;
  if (tid >= 224 * 64) return;
  int lane = tid & 63;
  int frag = tid >> 6;                 // 0..223 = [kblock*8 + ntile] per layer
  if (frag >= 96 && frag < 128) return;   // L1 kblocks 12..15: folded into b1p
  const float* W; int base_us; int lf;
  if (frag < 128)      { W = W1; base_us = L1_OFF / 2; lf = frag; }
  else if (frag < 160) { W = W2; base_us = L2_OFF / 2; lf = frag - 128; }
  else if (frag < 192) { W = W3; base_us = L3_OFF / 2; lf = frag - 160; }
  else                 { W = W4; base_us = L4_OFF / 2; lf = frag - 192; }
  int kb = lf >> 3, nt = lf & 7;
  int k0 = kb * 32 + (lane >> 4) * 8;
  int n  = nt * 16 + (lane & 15);
  unsigned int pk[4];
#pragma unroll
  for (int j = 0; j < 4; ++j) {
    unsigned int lo = f2bf(W[(size_t)(k0 + 2 * j    ) * D + n]);
    unsigned int hi = f2bf(W[(size_t)(k0 + 2 * j + 1) * D + n]);
    pk[j] = lo | (hi << 16);
  }
  *(uint4*)(ws + base_us + ((size_t)lf * 64 + lane) * 8) =
      make_uint4(pk[0], pk[1], pk[2], pk[3]);
}

__global__ __launch_bounds__(256, 4) void edge_mlp(
    const float* __restrict__ recv, const float* __restrict__ send,
    const float* __restrict__ edge,
    const float* __restrict__ b2, const float* __restrict__ b3,
    const float* __restrict__ b4,
    const unsigned short* __restrict__ ws,
    float* __restrict__ out)
{
  // per-wave private 8KB LDS slice for h (layers 2-4): 32 rows x 128 bf16, XOR-swizzled
  __shared__ __attribute__((aligned(16))) char smem[NW * 8192];
  const int lane = threadIdx.x & 63;
  const int wid  = threadIdx.x >> 6;
  char* wbuf = smem + wid * 8192;
  const int row0 = blockIdx.x * BM + wid * 32;   // this wave's first edge row
  const int arow = lane & 15;
  const int kgrp = lane >> 4;

  f32x4 acc[2][8];
#pragma unroll
  for (int m = 0; m < 2; ++m)
#pragma unroll
    for (int n = 0; n < 8; ++n) acc[m][n] = (f32x4)0.0f;

  // -------- layer 1: x = [recv | send | edge], K = 384, A-frags direct from global --------
#pragma unroll
  for (int c = 0; c < 3; ++c) {
    const float* src = (c == 0) ? recv : (c == 1) ? send : edge;
    const float* p0 = src + (size_t)(row0 + arow) * D + kgrp * 8;
    const float* p1 = p0 + (size_t)16 * D;
#pragma unroll
    for (int kk = 0; kk < 4; ++kk) {
      const unsigned short* wp =
          ws + L1_OFF / 2 + ((size_t)((c * 4 + kk) * 8) * 64 + lane) * 8;
      bf16x8 bfr[8];
#pragma unroll
      for (int n = 0; n < 8; ++n) bfr[n] = *(const bf16x8*)(wp + (size_t)n * 512);
      bf16x8 afr[2];
#pragma unroll
      for (int m = 0; m < 2; ++m) {
        const float* p = (m ? p1 : p0) + kk * 32;
        float4 v0 = *(const float4*)p;
        float4 v1 = *(const float4*)(p + 4);
        afr[m] = cvt8(v0, v1);
      }
#pragma unroll
      for (int m = 0; m < 2; ++m)
#pragma unroll
        for (int n = 0; n < 8; ++n)
          acc[m][n] = __builtin_amdgcn_mfma_f32_16x16x32_bf16(afr[m], bfr[n], acc[m][n], 0, 0, 0);
    }
  }

  // epilogue: bias + relu + bf16 -> wave's LDS slice (same-wave DS is in-order, no barrier)
  auto store_h = [&](const float* __restrict__ bias) {
#pragma unroll
    for (int n = 0; n < 8; ++n) {
      float bn = bias[n * 16 + arow];
      int colB = (n * 16 + arow) * 2;
#pragma unroll
      for (int m = 0; m < 2; ++m) {
#pragma unroll
        for (int rp = 0; rp < 4; rp += 2) {
          float x0 = fmaxf(acc[m][n][rp]     + bn, 0.0f);
          float x1 = fmaxf(acc[m][n][rp + 1] + bn, 0.0f);
          unsigned int u = cvtpk(x0, x1);
          int rw0 = m * 16 + kgrp * 4 + rp;
          int rw1 = rw0 + 1;
          int a0 = rw0 * 256 + (((colB & ~15) ^ ((rw0 & 7) << 4)) | (colB & 15));
          int a1 = rw1 * 256 + (((colB & ~15) ^ ((rw1 & 7) << 4)) | (colB & 15));
          *(unsigned short*)(wbuf + a0) = (unsigned short)u;
          *(unsigned short*)(wbuf + a1) = (unsigned short)(u >> 16);
        }
        acc[m][n] = (f32x4)0.0f;
      }
    }
  };

  auto do_layer = [&](int ws_us_off) {
#pragma unroll
    for (int kk = 0; kk < 4; ++kk) {
      const unsigned short* wp = ws + ws_us_off + ((size_t)(kk * 8) * 64 + lane) * 8;
      bf16x8 bfr[8];
#pragma unroll
      for (int n = 0; n < 8; ++n) bfr[n] = *(const bf16x8*)(wp + (size_t)n * 512);
      bf16x8 afr[2];
#pragma unroll
      for (int m = 0; m < 2; ++m) {
        int rl = m * 16 + arow;
        int kB = kk * 64 + kgrp * 16;
        afr[m] = *(const bf16x8*)(wbuf + rl * 256 + (kB ^ ((rl & 7) << 4)));
      }
#pragma unroll
      for (int m = 0; m < 2; ++m)
#pragma unroll
        for (int n = 0; n < 8; ++n)
          acc[m][n] = __builtin_amdgcn_mfma_f32_16x16x32_bf16(afr[m], bfr[n], acc[m][n], 0, 0, 0);
    }
  };

  const float* b1p = (const float*)(ws + B1P_US);
  store_h(b1p);
  do_layer(L2_OFF / 2);
  store_h(b2);
  do_layer(L3_OFF / 2);
  store_h(b3);
  do_layer(L4_OFF / 2);

  // final layer: bias, no relu, f32 store
#pragma unroll
  for (int n = 0; n < 8; ++n) {
    float bn = b4[n * 16 + arow];
#pragma unroll
    for (int m = 0; m < 2; ++m)
#pragma unroll
      for (int r = 0; r < 4; ++r) {
        int rw = m * 16 + kgrp * 4 + r;
        out[(size_t)(row0 + rw) * D + n * 16 + arow] = acc[m][n][r] + bn;
      }
  }
}

extern "C" void kernel_launch(void* const* d_in, const int* in_sizes, int n_in,
                              void* d_out, int out_size, void* d_ws, size_t ws_size,
                              hipStream_t stream)
{
  const float* recv = (const float*)d_in[0];
  const float* send = (const float*)d_in[1];
  const float* edge = (const float*)d_in[2];
  const float* glob = (const float*)d_in[3];
  const float* W1 = (const float*)d_in[4];
  const float* b1 = (const float*)d_in[5];
  const float* W2 = (const float*)d_in[6];
  const float* b2 = (const float*)d_in[7];
  const float* W3 = (const float*)d_in[8];
  const float* b3 = (const float*)d_in[9];
  const float* W4 = (const float*)d_in[10];
  const float* b4 = (const float*)d_in[11];
  unsigned short* ws = (unsigned short*)d_ws;

  prep_weights<<<57, 256, 0, stream>>>(W1, W2, W3, W4, b1, glob, ws);
  edge_mlp<<<E_EDGES / BM, 256, 0, stream>>>(recv, send, edge,
                                             b2, b3, b4, ws, (float*)d_out);
}

// Round 5
// 233.774 us; speedup vs baseline: 1.3395x; 1.3395x over previous
//
#include <hip/hip_runtime.h>

#define E_EDGES 327680
#define D 128
#define BM 128      // edges per block
#define NW 4        // waves per block (each wave owns 32 edges)

typedef __bf16 bf16x8 __attribute__((ext_vector_type(8)));
typedef float  f32x4  __attribute__((ext_vector_type(4)));

// may_alias access types: LDS h-buffer is written as u16/u32 and read as bf16x8.
// Without may_alias, TBAA lets the compiler hoist next-layer ds_reads above the
// epilogue ds_writes (R4 failure: absmax 0.279 at relaxed VGPR budget).
typedef unsigned short u16a __attribute__((may_alias));
typedef unsigned int   u32a __attribute__((may_alias));
typedef bf16x8 __attribute__((may_alias)) bf16x8a;
typedef uint2  __attribute__((may_alias)) uint2a;

// d_ws layout (bf16 weight fragments, B-operand order for mfma_f32_16x16x32_bf16):
//   per (kblock, ntile): 64 lanes x 16B, lane l holds W[k0+(l>>4)*8+j][ntile*16+(l&15)]
//   L1: kblocks 0..11 used (12..15 slot reused for b1p); L2/3/4: 4 kblocks each.
#define L1_OFF 0
#define L2_OFF 131072
#define L3_OFF 163840
#define L4_OFF 196608
#define B1P_US 49152   // u16 offset of f32 b1p[128] (= byte 98304, old L1 kblock-12 slot)

__device__ __forceinline__ unsigned short f2bf(float f) {
  unsigned int u = __builtin_bit_cast(unsigned int, f);
  u += 0x7fffu + ((u >> 16) & 1u);   // round-to-nearest-even
  return (unsigned short)(u >> 16);
}

__device__ __forceinline__ unsigned int cvtpk(float lo, float hi) {
  unsigned int r;
  asm("v_cvt_pk_bf16_f32 %0, %1, %2" : "=v"(r) : "v"(lo), "v"(hi));
  return r;
}

__device__ __forceinline__ bf16x8 cvt8(float4 a, float4 b) {
  union { unsigned int u[4]; bf16x8 v; } r;
  r.u[0] = cvtpk(a.x, a.y);
  r.u[1] = cvtpk(a.z, a.w);
  r.u[2] = cvtpk(b.x, b.y);
  r.u[3] = cvtpk(b.z, b.w);
  return r.v;
}

__global__ __launch_bounds__(256) void prep_weights(
    const float* __restrict__ W1, const float* __restrict__ W2,
    const float* __restrict__ W3, const float* __restrict__ W4,
    const float* __restrict__ b1, const float* __restrict__ glob,
    unsigned short* __restrict__ ws)
{
  if (blockIdx.x == 56) {
    // b1p[n] = b1[n] + sum_j g[j] * W1[384+j][n]
    int n = threadIdx.x;
    if (n < D) {
      float s = b1[n];
      for (int j = 0; j < D; ++j) s += glob[j] * W1[(size_t)(384 + j) * D + n];
      ((float*)(ws + B1P_US))[n] = s;
    }
    return;
  }
  int tid = blockIdx.x * 256 + threadIdx.x;
  if (tid >= 224 * 64) return;
  int lane = tid & 63;
  int frag = tid >> 6;                 // 0..223 = [kblock*8 + ntile] per layer
  if (frag >= 96 && frag < 128) return;   // L1 kblocks 12..15: folded into b1p
  const float* W; int base_us; int lf;
  if (frag < 128)      { W = W1; base_us = L1_OFF / 2; lf = frag; }
  else if (frag < 160) { W = W2; base_us = L2_OFF / 2; lf = frag - 128; }
  else if (frag < 192) { W = W3; base_us = L3_OFF / 2; lf = frag - 160; }
  else                 { W = W4; base_us = L4_OFF / 2; lf = frag - 192; }
  int kb = lf >> 3, nt = lf & 7;
  int k0 = kb * 32 + (lane >> 4) * 8;
  int n  = nt * 16 + (lane & 15);
  unsigned int pk[4];
#pragma unroll
  for (int j = 0; j < 4; ++j) {
    unsigned int lo = f2bf(W[(size_t)(k0 + 2 * j    ) * D + n]);
    unsigned int hi = f2bf(W[(size_t)(k0 + 2 * j + 1) * D + n]);
    pk[j] = lo | (hi << 16);
  }
  *(uint4*)(ws + base_us + ((size_t)lf * 64 + lane) * 8) =
      make_uint4(pk[0], pk[1], pk[2], pk[3]);
}

__global__ __launch_bounds__(256) void edge_mlp(
    const float* __restrict__ recv, const float* __restrict__ send,
    const float* __restrict__ edge,
    const float* __restrict__ b2, const float* __restrict__ b3,
    const float* __restrict__ b4,
    const unsigned short* __restrict__ ws,
    float* __restrict__ out)
{
  // per-wave private 8KB LDS slice for h (layers 2-4): 32 rows x 128 bf16, XOR-swizzled
  __shared__ __attribute__((aligned(16))) char smem[NW * 8192];
  const int lane = threadIdx.x & 63;
  const int wid  = threadIdx.x >> 6;
  char* wbuf = smem + wid * 8192;
  const int row0 = blockIdx.x * BM + wid * 32;   // this wave's first edge row
  const int arow = lane & 15;
  const int kgrp = lane >> 4;

  f32x4 acc[2][8];
#pragma unroll
  for (int m = 0; m < 2; ++m)
#pragma unroll
    for (int n = 0; n < 8; ++n) acc[m][n] = (f32x4)0.0f;

  // -------- layer 1: x = [recv | send | edge], K = 384, A-frags direct from global --------
#pragma unroll
  for (int c = 0; c < 3; ++c) {
    const float* src = (c == 0) ? recv : (c == 1) ? send : edge;
    const float* p0 = src + (size_t)(row0 + arow) * D + kgrp * 8;
    const float* p1 = p0 + (size_t)16 * D;
#pragma unroll
    for (int kk = 0; kk < 4; ++kk) {
      const unsigned short* wp =
          ws + L1_OFF / 2 + ((size_t)((c * 4 + kk) * 8) * 64 + lane) * 8;
      bf16x8 bfr[8];
#pragma unroll
      for (int n = 0; n < 8; ++n) bfr[n] = *(const bf16x8a*)(wp + (size_t)n * 512);
      bf16x8 afr[2];
#pragma unroll
      for (int m = 0; m < 2; ++m) {
        const float* p = (m ? p1 : p0) + kk * 32;
        float4 v0 = *(const float4*)p;
        float4 v1 = *(const float4*)(p + 4);
        afr[m] = cvt8(v0, v1);
      }
#pragma unroll
      for (int m = 0; m < 2; ++m)
#pragma unroll
        for (int n = 0; n < 8; ++n)
          acc[m][n] = __builtin_amdgcn_mfma_f32_16x16x32_bf16(afr[m], bfr[n], acc[m][n], 0, 0, 0);
    }
  }

  // epilogue: bias + relu + bf16 -> wave's LDS slice (same-wave DS pipe is in-order;
  // may_alias types + sched_barrier(0) keep the compiler from reordering around it)
  auto store_h = [&](const float* __restrict__ bias) {
#pragma unroll
    for (int n = 0; n < 8; ++n) {
      float bn = bias[n * 16 + arow];
      int colB = (n * 16 + arow) * 2;
#pragma unroll
      for (int m = 0; m < 2; ++m) {
#pragma unroll
        for (int rp = 0; rp < 4; rp += 2) {
          float x0 = fmaxf(acc[m][n][rp]     + bn, 0.0f);
          float x1 = fmaxf(acc[m][n][rp + 1] + bn, 0.0f);
          unsigned int u = cvtpk(x0, x1);
          int rw0 = m * 16 + kgrp * 4 + rp;
          int rw1 = rw0 + 1;
          int a0 = rw0 * 256 + (((colB & ~15) ^ ((rw0 & 7) << 4)) | (colB & 15));
          int a1 = rw1 * 256 + (((colB & ~15) ^ ((rw1 & 7) << 4)) | (colB & 15));
          *(u16a*)(wbuf + a0) = (unsigned short)u;
          *(u16a*)(wbuf + a1) = (unsigned short)(u >> 16);
        }
        acc[m][n] = (f32x4)0.0f;
      }
    }
    __builtin_amdgcn_sched_barrier(0);   // LDS writes must precede next layer's reads
  };

  auto do_layer = [&](int ws_us_off) {
#pragma unroll
    for (int kk = 0; kk < 4; ++kk) {
      const unsigned short* wp = ws + ws_us_off + ((size_t)(kk * 8) * 64 + lane) * 8;
      bf16x8 bfr[8];
#pragma unroll
      for (int n = 0; n < 8; ++n) bfr[n] = *(const bf16x8a*)(wp + (size_t)n * 512);
      bf16x8 afr[2];
#pragma unroll
      for (int m = 0; m < 2; ++m) {
        int rl = m * 16 + arow;
        int kB = kk * 64 + kgrp * 16;
        afr[m] = *(const bf16x8a*)(wbuf + rl * 256 + (kB ^ ((rl & 7) << 4)));
      }
#pragma unroll
      for (int m = 0; m < 2; ++m)
#pragma unroll
        for (int n = 0; n < 8; ++n)
          acc[m][n] = __builtin_amdgcn_mfma_f32_16x16x32_bf16(afr[m], bfr[n], acc[m][n], 0, 0, 0);
    }
    __builtin_amdgcn_sched_barrier(0);   // reads of h done before epilogue overwrites
  };

  const float* b1p = (const float*)(ws + B1P_US);
  store_h(b1p);
  do_layer(L2_OFF / 2);
  store_h(b2);
  do_layer(L3_OFF / 2);
  store_h(b3);
  do_layer(L4_OFF / 2);

  // final layer: bias, no relu, f32 store
#pragma unroll
  for (int n = 0; n < 8; ++n) {
    float bn = b4[n * 16 + arow];
#pragma unroll
    for (int m = 0; m < 2; ++m)
#pragma unroll
      for (int r = 0; r < 4; ++r) {
        int rw = m * 16 + kgrp * 4 + r;
        out[(size_t)(row0 + rw) * D + n * 16 + arow] = acc[m][n][r] + bn;
      }
  }
}

extern "C" void kernel_launch(void* const* d_in, const int* in_sizes, int n_in,
                              void* d_out, int out_size, void* d_ws, size_t ws_size,
                              hipStream_t stream)
{
  const float* recv = (const float*)d_in[0];
  const float* send = (const float*)d_in[1];
  const float* edge = (const float*)d_in[2];
  const float* glob = (const float*)d_in[3];
  const float* W1 = (const float*)d_in[4];
  const float* b1 = (const float*)d_in[5];
  const float* W2 = (const float*)d_in[6];
  const float* b2 = (const float*)d_in[7];
  const float* W3 = (const float*)d_in[8];
  const float* b3 = (const float*)d_in[9];
  const float* W4 = (const float*)d_in[10];
  const float* b4 = (const float*)d_in[11];
  unsigned short* ws = (unsigned short*)d_ws;

  prep_weights<<<57, 256, 0, stream>>>(W1, W2, W3, W4, b1, glob, ws);
  edge_mlp<<<E_EDGES / BM, 256, 0, stream>>>(recv, send, edge,
                                             b2, b3, b4, ws, (float*)d_out);
}